// Round 13
// baseline (87.156 us; speedup 1.0000x reference)
//
#include <hip/hip_runtime.h>
#include <hip/hip_bf16.h>

typedef __attribute__((ext_vector_type(8))) short short8;   // 8 x bf16 (4 VGPR)
typedef __attribute__((ext_vector_type(4))) float f32x4;
typedef __attribute__((ext_vector_type(4))) int   i32x4;

#define KD 4096
#define ND 16384
#define MD 128

// round-to-nearest-even f32 -> bf16 bits
__device__ __forceinline__ ushort f2bf_rn(float f) {
    unsigned u = __float_as_uint(f);
    u += 0x7FFFu + ((u >> 16) & 1u);
    return (ushort)(u >> 16);
}

// exact for |v| <= 127: int -> f32 -> truncate to bf16 (small ints have zero low mantissa bits)
__device__ __forceinline__ ushort i2bf(int v) {
    return (ushort)(__float_as_uint((float)v) >> 16);
}

// Pack x[128][4096] f32 into bf16 MFMA A-fragment order (verified r1/r3):
// xp byte layout: kb*8192 + mt*1024 + lane*16, holding x[16*mt+(lane&15)][32*kb+8*(lane>>4)+j]
__global__ __launch_bounds__(256) void pack_x_kernel(const float* __restrict__ x,
                                                     ushort* __restrict__ xp) {
    int tid  = blockIdx.x * 256 + threadIdx.x;   // 0..65535
    int lane = tid & 63;
    int mt   = (tid >> 6) & 7;
    int kb   = tid >> 9;                          // 0..127
    int m = (mt << 4) + (lane & 15);
    int k = (kb << 5) + ((lane >> 4) << 3);
    const f32x4* src = reinterpret_cast<const f32x4*>(x + (size_t)m * KD + k);
    f32x4 a = src[0];
    f32x4 b = src[1];
    short8 v;
    v[0] = (short)f2bf_rn(a[0]); v[1] = (short)f2bf_rn(a[1]);
    v[2] = (short)f2bf_rn(a[2]); v[3] = (short)f2bf_rn(a[3]);
    v[4] = (short)f2bf_rn(b[0]); v[5] = (short)f2bf_rn(b[1]);
    v[6] = (short)f2bf_rn(b[2]); v[7] = (short)f2bf_rn(b[3]);
    *reinterpret_cast<short8*>(xp + (size_t)tid * 8) = v;
}

#define GLOAD_LDS16(g, l)                                                        \
    __builtin_amdgcn_global_load_lds((const __attribute__((address_space(1))) void*)(g), \
                                     (__attribute__((address_space(3))) void*)(l), 16, 0, 0)

// Producer/consumer wave specialization (verified r10), W-only LDS staging.
// Block = 512 threads (8 waves), grid 256 (1 block/CU). Tile: 64 cols x 128 rows x full K.
//   waves 0..3  CONSUMERS: 16 cols each, acc[8]; A fragments loaded DIRECTLY global->reg
//               (xp is L2/L3-resident; all 4 consumer waves read identical addresses ->
//               L1 broadcast). A loads are consumed within the phase, so the
//               __syncthreads vmcnt drain stays ~free. W from LDS as in r10.
//   waves 4..7  PRODUCERS: W only, K-chunk=128 (512 B contiguous per col = 2x burst
//               vs r10), depth-3, 8 gload_lds per stage, issue 2 ahead,
//               raw s_barrier + counted vmcnt(8) (no ds_reads in producer waves).
// LDS: W 3 x 32 KiB = 96 KiB, stage s -> buffer s%3. 32 phases (half of r10's 64).
__global__ __launch_bounds__(512) void gemm_kernel(const int* __restrict__ wgt,
                                                   const ushort* __restrict__ xp,
                                                   const float* __restrict__ scales,
                                                   const float* __restrict__ bias,
                                                   float* __restrict__ out) {
    __shared__ __align__(16) char lds[98304];

    const int tid  = threadIdx.x;
    const int lane = tid & 63;
    const int w    = tid >> 6;          // wave 0..7
    const int n0   = blockIdx.x << 6;   // 256 blocks x 64 cols
    const int cl   = lane & 15;
    const int cq   = lane >> 4;         // 0..3

    if (w >= 4) {
        // ================= PRODUCER (W only) =================
        const int p = w - 4;            // 0..3 -> cols [16p, 16p+16)
        // 8 issues/stage; issue i, lane l -> LDS linear byte p*8192 + i*1024 + l*16
        //   => col c = 16p + 2i + (l>>5), inner = (l&31)*16.
        // Target layout (verified r3, extended to 512B cols):
        //   inner(c,k) = (4k) ^ ((c&7)<<4)  =>  k = ((l&31)<<2) ^ ((c&7)<<2).
        const int* wsrc[8];
#pragma unroll
        for (int i = 0; i < 8; ++i) {
            int c = (p << 4) + (i << 1) + (lane >> 5);
            int k = ((lane & 31) << 2) ^ ((c & 7) << 2);
            wsrc[i] = wgt + (size_t)(n0 + c) * KD + k;
        }
        char* dW = lds + (p << 13);     // + b*32768 + i*1024 (+ lane*16 by HW)

#define STAGE(t, b) do {                                                        \
            const int _k0 = (t) * 128;                                          \
            char* _d = dW + (b) * 32768;                                        \
            _Pragma("unroll")                                                   \
            for (int _i = 0; _i < 8; ++_i)                                      \
                GLOAD_LDS16(wsrc[_i] + _k0, _d + _i * 1024);                    \
        } while (0)

        STAGE(0, 0);
        STAGE(1, 1);
        asm volatile("s_waitcnt vmcnt(8)" ::: "memory");   // stage 0 landed
        __builtin_amdgcn_s_barrier();                       // entry barrier

        int b2 = 2;                      // buffer of stage t+2
#pragma unroll 1
        for (int t = 0; t < 32; ++t) {
            if (t + 2 < 32) {
                STAGE(t + 2, b2);
                asm volatile("s_waitcnt vmcnt(8)" ::: "memory");  // stage t+1 landed
            } else if (t + 1 < 32) {
                asm volatile("s_waitcnt vmcnt(0)" ::: "memory");  // stage 31 landed
            }
            __builtin_amdgcn_s_barrier();
            b2 = (b2 == 2) ? 0 : b2 + 1;
        }
#undef STAGE
        return;   // producers write no output
    }

    // ================= CONSUMER (waves 0..3) =================
    f32x4 acc[8];
#pragma unroll
    for (int i = 0; i < 8; ++i) acc[i] = (f32x4){0.f, 0.f, 0.f, 0.f};

    // W read base: col (16w+cl), 512 B/col, swizzled inner (verified pattern)
    const char* rW = lds + (((w << 4) + cl) << 9);          // + b*32768 + inner
    const unsigned sw  = (unsigned)((cl & 7) << 4);
    const unsigned q32 = (unsigned)(cq << 5);
    // A source: chunk t covers bytes t*32768..; kbl j at j*8192, mt at mt*1024
    const char* ax = (const char*)xp + (lane << 4);

    __syncthreads();                                        // entry barrier

    int bc = 0;
#pragma unroll 1
    for (int t = 0; t < 32; ++t) {
        const char* wb = rW + bc * 32768;
        const char* at = ax + (size_t)t * 32768;
#pragma unroll
        for (int j = 0; j < 4; ++j) {                       // kbl within K=128
            // A fragments: 8 x 16B direct global->reg (L1/L2-served)
            short8 af[8];
            const char* aj = at + j * 8192;
#pragma unroll
            for (int mt = 0; mt < 8; ++mt)
                af[mt] = *reinterpret_cast<const short8*>(aj + mt * 1024);
            // W fragment from LDS
            unsigned off = (unsigned)((j << 7) + q32) ^ sw;
            i32x4 lo = *reinterpret_cast<const i32x4*>(wb + off);
            i32x4 hi = *reinterpret_cast<const i32x4*>(wb + (off ^ 16u));
            short8 bf;
            bf[0] = (short)i2bf(lo[0]); bf[1] = (short)i2bf(lo[1]);
            bf[2] = (short)i2bf(lo[2]); bf[3] = (short)i2bf(lo[3]);
            bf[4] = (short)i2bf(hi[0]); bf[5] = (short)i2bf(hi[1]);
            bf[6] = (short)i2bf(hi[2]); bf[7] = (short)i2bf(hi[3]);
#pragma unroll
            for (int mt = 0; mt < 8; ++mt)
                acc[mt] = __builtin_amdgcn_mfma_f32_16x16x32_bf16(af[mt], bf, acc[mt], 0, 0, 0);
        }
        __syncthreads();
        bc = (bc == 2) ? 0 : bc + 1;
    }

    // ---- epilogue: scale + bias, direct store (block owns 128 x 64 tile) ----
    const int ncol = n0 + (w << 4) + cl;
    const float s  = scales[ncol] * (1.0f / 127.0f);
    const float bv = bias[ncol];
    const int rb = cq << 2;
#pragma unroll
    for (int mt = 0; mt < 8; ++mt) {
#pragma unroll
        for (int r = 0; r < 4; ++r) {
            int mg = (mt << 4) + rb + r;
            out[(size_t)mg * ND + ncol] = acc[mt][r] * s + bv;
        }
    }
}

extern "C" void kernel_launch(void* const* d_in, const int* in_sizes, int n_in,
                              void* d_out, int out_size, void* d_ws, size_t ws_size,
                              hipStream_t stream) {
    const float* x      = (const float*)d_in[0];
    const int*   wgt    = (const int*)d_in[1];     // int8 promoted to int32 by harness
    const float* scales = (const float*)d_in[2];
    const float* bias   = (const float*)d_in[3];
    float* out = (float*)d_out;
    ushort* xp = (ushort*)d_ws;                    // 1 MiB bf16 packed x

    pack_x_kernel<<<MD * KD / (8 * 256), 256, 0, stream>>>(x, xp);
    gemm_kernel<<<256, 512, 0, stream>>>(wgt, xp, scales, bias, out);
}

// Round 14
// 58.450 us; speedup vs baseline: 1.4911x; 1.4911x over previous
//
#include <hip/hip_runtime.h>
#include <hip/hip_bf16.h>

typedef __attribute__((ext_vector_type(8))) short short8;   // 8 x bf16 (4 VGPR)
typedef __attribute__((ext_vector_type(4))) float f32x4;
typedef __attribute__((ext_vector_type(4))) int   i32x4;

#define KD 4096
#define ND 16384
#define MD 128

// round-to-nearest-even f32 -> bf16 bits
__device__ __forceinline__ ushort f2bf_rn(float f) {
    unsigned u = __float_as_uint(f);
    u += 0x7FFFu + ((u >> 16) & 1u);
    return (ushort)(u >> 16);
}

// exact for |v| <= 127: int -> f32 -> truncate to bf16 (small ints have zero low mantissa bits)
__device__ __forceinline__ ushort i2bf(int v) {
    return (ushort)(__float_as_uint((float)v) >> 16);
}

// Pack x[128][4096] f32 into bf16 MFMA A-fragment order (verified r1/r3):
// xp[kb][mt][lane][j] = x[16*mt + (lane&15)][32*kb + 8*(lane>>4) + j]   (1 MiB)
__global__ __launch_bounds__(256) void pack_x_kernel(const float* __restrict__ x,
                                                     ushort* __restrict__ xp) {
    int tid  = blockIdx.x * 256 + threadIdx.x;   // 0..65535
    int lane = tid & 63;
    int mt   = (tid >> 6) & 7;
    int kb   = tid >> 9;                          // 0..127
    int m = (mt << 4) + (lane & 15);
    int k = (kb << 5) + ((lane >> 4) << 3);
    const f32x4* src = reinterpret_cast<const f32x4*>(x + (size_t)m * KD + k);
    f32x4 a = src[0];
    f32x4 b = src[1];
    short8 v;
    v[0] = (short)f2bf_rn(a[0]); v[1] = (short)f2bf_rn(a[1]);
    v[2] = (short)f2bf_rn(a[2]); v[3] = (short)f2bf_rn(a[3]);
    v[4] = (short)f2bf_rn(b[0]); v[5] = (short)f2bf_rn(b[1]);
    v[6] = (short)f2bf_rn(b[2]); v[7] = (short)f2bf_rn(b[3]);
    *reinterpret_cast<short8*>(xp + (size_t)tid * 8) = v;
}

#define GLOAD_LDS16(g, l)                                                        \
    __builtin_amdgcn_global_load_lds((const __attribute__((address_space(1))) void*)(g), \
                                     (__attribute__((address_space(3))) void*)(l), 16, 0, 0)

// Producer/consumer wave specialization — r10 verbatim except consumer wave tiling.
// Block = 512 threads (8 waves), grid 256 (1 block/CU). Tile: 64 cols x 128 rows x full K.
//   waves 0..3  CONSUMERS: wave tile 64 rows x 32 cols (wr=w>>1 row-half, wc=w&1
//               col-half): per j-block 4 A-frags x 2 W-frags = 8 MFMA with 8 ds_reads
//               (r10's 128x16 tile needed 10) -> 16 reads/phase/wave vs 20, -20% LDS
//               port occupancy. acc[4][2]. Plain __syncthreads() (vmcnt queue empty).
//   waves 4..7  PRODUCERS: byte-identical to r10 — 8 gload_lds per stage (4 A + 4 W),
//               depth-3, issue 2 ahead, raw s_barrier + counted vmcnt(8).
// LDS: A 3x16K [0,48K) + W 3x16K [48K,96K), stage s -> buffer s%3.
__global__ __launch_bounds__(512) void gemm_kernel(const int* __restrict__ wgt,
                                                   const ushort* __restrict__ xp,
                                                   const float* __restrict__ scales,
                                                   const float* __restrict__ bias,
                                                   float* __restrict__ out) {
    __shared__ __align__(16) char lds[98304];

    const int tid  = threadIdx.x;
    const int lane = tid & 63;
    const int w    = tid >> 6;          // wave 0..7
    const int n0   = blockIdx.x << 6;   // 256 blocks x 64 cols
    const int cl   = lane & 15;
    const int cq   = lane >> 4;         // 0..3

    if (w >= 4) {
        // ================= PRODUCER (r10 verbatim) =================
        const int p = w - 4;            // 0..3
        const char* asrc = (const char*)xp + (p << 12) + (lane << 4);
        const int* wsrc0;
        const int* wsrc1;
        const int* wsrc2;
        const int* wsrc3;
        {
            int c0 = (p << 4) + 0  + cq;
            int c1 = (p << 4) + 4  + cq;
            int c2 = (p << 4) + 8  + cq;
            int c3 = (p << 4) + 12 + cq;
            wsrc0 = wgt + (size_t)(n0 + c0) * KD + ((cl ^ (c0 & 7)) << 2);
            wsrc1 = wgt + (size_t)(n0 + c1) * KD + ((cl ^ (c1 & 7)) << 2);
            wsrc2 = wgt + (size_t)(n0 + c2) * KD + ((cl ^ (c2 & 7)) << 2);
            wsrc3 = wgt + (size_t)(n0 + c3) * KD + ((cl ^ (c3 & 7)) << 2);
        }
        char* dA = lds + (p << 12);             // + b*16384 + i*1024
        char* dW = lds + 49152 + (p << 12);     // + b*16384 + i*1024

#define STAGE(t, b) do {                                                        \
            const char* _as = asrc + (size_t)(t) * 16384;                       \
            char* _dA = dA + (b) * 16384;                                       \
            GLOAD_LDS16(_as,        _dA);                                       \
            GLOAD_LDS16(_as + 1024, _dA + 1024);                                \
            GLOAD_LDS16(_as + 2048, _dA + 2048);                                \
            GLOAD_LDS16(_as + 3072, _dA + 3072);                                \
            const int _k0 = (t) * 64;                                           \
            char* _dW = dW + (b) * 16384;                                       \
            GLOAD_LDS16(wsrc0 + _k0, _dW);                                      \
            GLOAD_LDS16(wsrc1 + _k0, _dW + 1024);                               \
            GLOAD_LDS16(wsrc2 + _k0, _dW + 2048);                               \
            GLOAD_LDS16(wsrc3 + _k0, _dW + 3072);                               \
        } while (0)

        STAGE(0, 0);
        STAGE(1, 1);
        asm volatile("s_waitcnt vmcnt(8)" ::: "memory");   // stage 0 landed
        __builtin_amdgcn_s_barrier();                       // entry barrier

        int b2 = 2;                      // buffer of stage t+2
#pragma unroll 1
        for (int t = 0; t < 64; ++t) {
            if (t + 2 < 64) {
                STAGE(t + 2, b2);
                asm volatile("s_waitcnt vmcnt(8)" ::: "memory");  // stage t+1 landed
            } else if (t + 1 < 64) {
                asm volatile("s_waitcnt vmcnt(0)" ::: "memory");  // stage 63 landed
            }
            __builtin_amdgcn_s_barrier();
            b2 = (b2 == 2) ? 0 : b2 + 1;
        }
#undef STAGE
        return;   // producers write no output
    }

    // ================= CONSUMER (waves 0..3): 64 rows x 32 cols =================
    const int wr = w >> 1;              // row-half: m-tiles 4wr..4wr+3
    const int wc = w & 1;               // col-half: groups 2wc, 2wc+1

    f32x4 acc[4][2];
#pragma unroll
    for (int i = 0; i < 4; ++i) {
        acc[i][0] = (f32x4){0.f, 0.f, 0.f, 0.f};
        acc[i][1] = (f32x4){0.f, 0.f, 0.f, 0.f};
    }

    // read bases (verified layouts, r10)
    const char* rA  = lds + (wr << 12) + (lane << 4);   // + b*16384 + j*8192 + m*1024
    const int g0 = wc << 1;
    const char* rW0 = lds + 49152 + ((((g0 + 0) << 4) + cl) << 8);  // + b*16384 + inner
    const char* rW1 = lds + 49152 + ((((g0 + 1) << 4) + cl) << 8);
    const unsigned sw  = (unsigned)((cl & 7) << 4);
    const unsigned q32 = (unsigned)(cq << 5);

    __syncthreads();                                        // entry barrier (vmcnt empty)

    int bc = 0;
#pragma unroll 1
    for (int t = 0; t < 64; ++t) {
        const char* ab  = rA  + bc * 16384;
        const char* wb0 = rW0 + bc * 16384;
        const char* wb1 = rW1 + bc * 16384;
#pragma unroll
        for (int j = 0; j < 2; ++j) {
            unsigned off = (unsigned)((j << 7) + q32) ^ sw;
            i32x4 lo0 = *reinterpret_cast<const i32x4*>(wb0 + off);
            i32x4 hi0 = *reinterpret_cast<const i32x4*>(wb0 + (off ^ 16u));
            i32x4 lo1 = *reinterpret_cast<const i32x4*>(wb1 + off);
            i32x4 hi1 = *reinterpret_cast<const i32x4*>(wb1 + (off ^ 16u));
            short8 bf0, bf1;
            bf0[0] = (short)i2bf(lo0[0]); bf0[1] = (short)i2bf(lo0[1]);
            bf0[2] = (short)i2bf(lo0[2]); bf0[3] = (short)i2bf(lo0[3]);
            bf0[4] = (short)i2bf(hi0[0]); bf0[5] = (short)i2bf(hi0[1]);
            bf0[6] = (short)i2bf(hi0[2]); bf0[7] = (short)i2bf(hi0[3]);
            bf1[0] = (short)i2bf(lo1[0]); bf1[1] = (short)i2bf(lo1[1]);
            bf1[2] = (short)i2bf(lo1[2]); bf1[3] = (short)i2bf(lo1[3]);
            bf1[4] = (short)i2bf(hi1[0]); bf1[5] = (short)i2bf(hi1[1]);
            bf1[6] = (short)i2bf(hi1[2]); bf1[7] = (short)i2bf(hi1[3]);
            const char* aj = ab + j * 8192;
#pragma unroll
            for (int m = 0; m < 4; ++m) {
                short8 af = *reinterpret_cast<const short8*>(aj + m * 1024);
                acc[m][0] = __builtin_amdgcn_mfma_f32_16x16x32_bf16(af, bf0, acc[m][0], 0, 0, 0);
                acc[m][1] = __builtin_amdgcn_mfma_f32_16x16x32_bf16(af, bf1, acc[m][1], 0, 0, 0);
            }
        }
        __syncthreads();
        bc = (bc == 2) ? 0 : bc + 1;
    }

    // ---- epilogue: scale + bias, direct store ----
    const int nc0 = n0 + ((g0 + 0) << 4) + cl;
    const int nc1 = n0 + ((g0 + 1) << 4) + cl;
    const float s0  = scales[nc0] * (1.0f / 127.0f);
    const float s1  = scales[nc1] * (1.0f / 127.0f);
    const float bv0 = bias[nc0];
    const float bv1 = bias[nc1];
    const int rb = cq << 2;
#pragma unroll
    for (int m = 0; m < 4; ++m) {
#pragma unroll
        for (int r = 0; r < 4; ++r) {
            int mg = (wr << 6) + (m << 4) + rb + r;
            out[(size_t)mg * ND + nc0] = acc[m][0][r] * s0 + bv0;
            out[(size_t)mg * ND + nc1] = acc[m][1][r] * s1 + bv1;
        }
    }
}

extern "C" void kernel_launch(void* const* d_in, const int* in_sizes, int n_in,
                              void* d_out, int out_size, void* d_ws, size_t ws_size,
                              hipStream_t stream) {
    const float* x      = (const float*)d_in[0];
    const int*   wgt    = (const int*)d_in[1];     // int8 promoted to int32 by harness
    const float* scales = (const float*)d_in[2];
    const float* bias   = (const float*)d_in[3];
    float* out = (float*)d_out;
    ushort* xp = (ushort*)d_ws;                    // 1 MiB bf16 packed x

    pack_x_kernel<<<MD * KD / (8 * 256), 256, 0, stream>>>(x, xp);
    gemm_kernel<<<256, 512, 0, stream>>>(wgt, xp, scales, bias, out);
}